// Round 18
// baseline (1097.428 us; speedup 1.0000x reference)
//
#include <hip/hip_runtime.h>
#include <stdint.h>

// WeightOnlyInt4Linear: y = X @ dequant(Q)^T ; M=8192, K=4096, N=11008, G=128.
// Round 18: hybrid operand placement at 2 blocks/CU.
//  - A in LDS only: 4-buffer ring (4 x 16KB), staged 2 tiles ahead (r17's
//    proven 64B-row swizzle), BK=32.
//  - B direct global->register from fragment-tiled Wb (r15's proven prepass
//    layout): 4 x global_load_dwordx4 per wave per tile, loaded 1 tile ahead.
//  - 2 blocks/CU (256x128 tile, 8 waves, 64x64/wave, acc=64 VGPR, ~120 total).
// vmcnt ring (in-order): entering t = {stage(t+1)[2], B(t)[4]}; tile adds
// stage(t+2)[2]; VMW(2) drains stage(t+1)+B(t). Tiles 126/127: VMW(0).

typedef __attribute__((ext_vector_type(8))) short short8;
typedef __attribute__((ext_vector_type(4))) float float4v;
typedef __attribute__((ext_vector_type(4))) int int4v;
typedef __attribute__((ext_vector_type(2))) float float2v;
typedef __attribute__((ext_vector_type(4))) unsigned short ushort4v;

static constexpr int M_ = 8192;
static constexpr int K_ = 4096;
static constexpr int N_ = 11008;

__device__ __forceinline__ unsigned short f2bf(float f) {
    union { float f; uint32_t u; } v;
    v.f = f;
    uint32_t u = v.u;
    u += 0x7fffu + ((u >> 16) & 1u);  // RNE
    return (unsigned short)(u >> 16);
}

__device__ __forceinline__ void gload16(const void* g, void* l) {
    __builtin_amdgcn_global_load_lds(
        (const __attribute__((address_space(1))) uint32_t*)g,
        (__attribute__((address_space(3))) uint32_t*)l, 16, 0, 0);
}

// ---------------- Prepass 1: X fp32 -> bf16 ----------------
__global__ __launch_bounds__(256) void cvt_x_kernel(const float* __restrict__ X,
                                                    unsigned short* __restrict__ Xb) {
    const int i = blockIdx.x * 256 + threadIdx.x;
    const float4v a = ((const float4v*)X)[2 * (size_t)i];
    const float4v b = ((const float4v*)X)[2 * (size_t)i + 1];
    short8 o;
    #pragma unroll
    for (int j = 0; j < 4; ++j) o[j] = (short)f2bf(a[j]);
    #pragma unroll
    for (int j = 0; j < 4; ++j) o[4 + j] = (short)f2bf(b[j]);
    ((short8*)Xb)[(size_t)i] = o;
}

// ---------------- Prepass 2: W int4 -> bf16, FRAGMENT-TILED (r15-proven) ----
// Wb[nb][kb][lane][j] : n = nb*16 + (lane&15), k = kb*32 + (lane>>4)*8 + j.
__global__ __launch_bounds__(256) void deq_w_kernel(const int* __restrict__ Q,
                                                    const float* __restrict__ SZ,
                                                    unsigned short* __restrict__ Wb) {
    const int i = blockIdx.x * 256 + threadIdx.x;  // < N*K/8 = 5,636,096
    const int lane = i & 63;
    const int rest = i >> 6;
    const int kb = rest & 127;       // K/32 = 128
    const int nb = rest >> 7;        // N/16 = 688
    const int n = nb * 16 + (lane & 15);
    const int k0 = kb * 32 + (lane >> 4) * 8;
    const int g = kb >> 2;           // G=128 -> 4 kb per group
    const float2v sz = *(const float2v*)(SZ + ((size_t)g * N_ + n) * 2);
    const float s = sz[0], z = sz[1];
    const int4v q0 = *(const int4v*)(Q + (size_t)n * K_ + k0);
    const int4v q1 = *(const int4v*)(Q + (size_t)n * K_ + k0 + 4);
    short8 o;
    #pragma unroll
    for (int j = 0; j < 4; ++j) o[j] = (short)f2bf((float)(q0[j] - 8) * s + z);
    #pragma unroll
    for (int j = 0; j < 4; ++j) o[4 + j] = (short)f2bf((float)(q1[j] - 8) * s + z);
    ((short8*)Wb)[(size_t)i] = o;
}

// ---------------- 256x128 GEMM, A-LDS ring + B-reg, 2 blocks/CU ----------------
// LDS: 4 bufs x 16KB (A only), rows 64 B. phys 16B-slot = lg ^ ((row>>1)&3).

#define SBAR() __builtin_amdgcn_sched_barrier(0)
#define VMW(n) asm volatile("s_waitcnt vmcnt(" #n ")" ::: "memory")
#define LGKM0() asm volatile("s_waitcnt lgkmcnt(0)" ::: "memory")
#define BARRIER() __builtin_amdgcn_s_barrier()

__global__ __launch_bounds__(512, 4) void gemm_bf16_hyb(
    const unsigned short* __restrict__ Agl,  // [M][K] bf16
    const unsigned short* __restrict__ Wt,   // fragment-tiled Wb
    float* __restrict__ C) {
    __shared__ alignas(16) unsigned short lds[32768];  // 64 KiB = 4 x 16KB

    const int tid = threadIdx.x;
    const int lane = tid & 63;
    const int wid = tid >> 6;   // 0..7
    const int wr = wid >> 1;    // 0..3 -> rows wr*64..+63
    const int wc = wid & 1;     // 0..1 -> cols wc*64..+63

    // T1: XCD swizzle over 2752 = 8*344 blocks.
    const int bid = blockIdx.x;
    const int wg = (bid & 7) * 344 + (bid >> 3);
    const int mt = wg / 86;
    const int nt = wg % 86;
    const int row0 = mt * 256;
    const int col0 = nt * 128;

    // A staging lane geometry (r17-proven): 16 rows x 64 B per gload16.
    const int srow = lane >> 2;
    const int kc = ((lane & 3) ^ ((lane >> 3) & 3)) * 8;

    // A read lane geometry: row = wr*64 + l15 (+ mf*16); slot = lg swizzled.
    const int l15 = lane & 15;
    const int lg = lane >> 4;
    const int pslot = (lg ^ ((l15 >> 1) & 3)) << 4;
    const int aB = (wr * 64 + l15) * 64 + pslot;  // + mf*1024 + buf*16384

    const char* ldsB = (const char*)lds;
    unsigned short* ldsU = lds;
    const char* AglB = (const char*)Agl;
    const char* WtB = (const char*)Wt;

    // A staging streams (+64 B/tile).
    uint32_t sa0 = (uint32_t)(row0 + wid * 32 + 0 + srow) * (K_ * 2) + (uint32_t)kc * 2;
    uint32_t sa1 = (uint32_t)(row0 + wid * 32 + 16 + srow) * (K_ * 2) + (uint32_t)kc * 2;

    // B fragment streams: nb = nt*8 + wc*4 + nf; byte = ((nb*128 + t)*64+lane)*16.
#define BOFF(nf) \
    (uint32_t)(((uint32_t)(nt * 8 + wc * 4 + (nf)) * 128 * 64 + lane) * 16)
    uint32_t bo0 = BOFF(0), bo1 = BOFF(1), bo2 = BOFF(2), bo3 = BOFF(3);
#undef BOFF

    float4v acc[4][4] = {};
    short8 af[4], bf[4];

    auto stage = [&](int b) {  // 2 gload16: rows wid*32..+31 -> buf b
        gload16(AglB + sa0, ldsU + b * 8192 + (wid * 32 + 0) * 32);  sa0 += 64;
        gload16(AglB + sa1, ldsU + b * 8192 + (wid * 32 + 16) * 32); sa1 += 64;
    };
    auto loadB = [&]() {  // next tile's 4 B fragments -> bf
        bf[0] = *(const short8*)(WtB + bo0); bo0 += 1024;
        bf[1] = *(const short8*)(WtB + bo1); bo1 += 1024;
        bf[2] = *(const short8*)(WtB + bo2); bo2 += 1024;
        bf[3] = *(const short8*)(WtB + bo3); bo3 += 1024;
    };

    // Prologue: stage A(0)->buf0, A(1)->buf1; load B(0); drain A(0); barrier.
    stage(0); stage(1);
    SBAR();
    loadB();  // B(0)
    SBAR();
    VMW(2);   // drains stage(0), stage(1), B(0)[0..1]; leaves B(0)[2..3]
    BARRIER(); SBAR();

    // Tile t (BUF=t&3): stage(t+2)->buf[(t+2)&3]; 4 ds_read A(t); lgkm0;
    // VMW(W) [steady 2: drains stage(t+1)+B(t)]; 16 MFMA; loadB B(t+1); bar.
#define KTILE(BUF, DN, W, LB)                                                 \
    {                                                                         \
        if (DN) stage(((BUF) + 2) & 3);                                       \
        SBAR();                                                               \
        _Pragma("unroll")                                                     \
        for (int mf = 0; mf < 4; ++mf)                                        \
            af[mf] = *(const short8*)(ldsB + (BUF) * 16384 + mf * 1024 + aB); \
        LGKM0(); SBAR();                                                      \
        VMW(W); SBAR();                                                       \
        __builtin_amdgcn_s_setprio(1);                                        \
        _Pragma("unroll")                                                     \
        for (int mf = 0; mf < 4; ++mf)                                        \
            _Pragma("unroll")                                                 \
            for (int nf = 0; nf < 4; ++nf)                                    \
                acc[mf][nf] = __builtin_amdgcn_mfma_f32_16x16x32_bf16(        \
                    af[mf], bf[nf], acc[mf][nf], 0, 0, 0);                    \
        __builtin_amdgcn_s_setprio(0);                                        \
        SBAR();                                                               \
        if (LB) loadB();                                                      \
        SBAR();                                                               \
        BARRIER(); SBAR();                                                    \
    }

    for (int t2 = 0; t2 < 124; t2 += 4) {  // tiles 0..123
        KTILE(0, 1, 2, 1);
        KTILE(1, 1, 2, 1);
        KTILE(2, 1, 2, 1);
        KTILE(3, 1, 2, 1);
    }
    KTILE(0, 1, 2, 1);  // t=124: stages 126, loads B(125)
    KTILE(1, 1, 2, 1);  // t=125: stages 127, loads B(126)
    KTILE(2, 0, 0, 1);  // t=126: no stage; VMW(0); loads B(127)
    KTILE(3, 0, 0, 0);  // t=127: pure compute
#undef KTILE

    // Epilogue: D map col=lane&15, row=(lane>>4)*4+j (m89-verified).
    const int lrow = lg * 4;
    #pragma unroll
    for (int mf = 0; mf < 4; ++mf)
        #pragma unroll
        for (int nf = 0; nf < 4; ++nf)
            #pragma unroll
            for (int j = 0; j < 4; ++j) {
                const int r = row0 + wr * 64 + mf * 16 + lrow + j;
                const int c = col0 + wc * 64 + nf * 16 + l15;
                C[(size_t)r * N_ + c] = acc[mf][nf][j];
            }
}

// ---------------- Fallback: round-1 fused kernel ----------------
static constexpr int LDSS = 40;

__global__ __launch_bounds__(256, 2) void w4_gemm_fused(
    const float* __restrict__ X, const int* __restrict__ Q,
    const float* __restrict__ SZ, float* __restrict__ C) {
    __shared__ alignas(16) unsigned short As[128 * LDSS];
    __shared__ alignas(16) unsigned short Ws[128 * LDSS];
    const int tid = threadIdx.x;
    const int lane = tid & 63;
    const int wid = tid >> 6;
    const int wrr = wid >> 1;
    const int wcc = wid & 1;
    const int row0 = blockIdx.x * 128;
    const int col0 = blockIdx.y * 128;
    float4v acc[4][4] = {};
    float4v a_reg[4];
    int4v q_reg[4];
    float2v sz_reg[4];

    auto load_tile = [&](int kb) {
        const int g = kb >> 7;
        #pragma unroll
        for (int i = 0; i < 4; ++i) {
            const int idx = tid + 256 * i;
            const int r = idx >> 3;
            const int v = idx & 7;
            a_reg[i] = *(const float4v*)(X + (size_t)(row0 + r) * K_ + kb + v * 4);
            q_reg[i] = *(const int4v*)(Q + (size_t)(col0 + r) * K_ + kb + v * 4);
            sz_reg[i] = *(const float2v*)(SZ + ((size_t)g * N_ + (col0 + r)) * 2);
        }
    };
    auto write_tile = [&]() {
        #pragma unroll
        for (int i = 0; i < 4; ++i) {
            const int idx = tid + 256 * i;
            const int r = idx >> 3;
            const int v = idx & 7;
            ushort4v ab, wb;
            #pragma unroll
            for (int j = 0; j < 4; ++j) ab[j] = f2bf(a_reg[i][j]);
            const float s = sz_reg[i][0];
            const float z = sz_reg[i][1];
            #pragma unroll
            for (int j = 0; j < 4; ++j) wb[j] = f2bf((float)(q_reg[i][j] - 8) * s + z);
            *(ushort4v*)(&As[r * LDSS + v * 4]) = ab;
            *(ushort4v*)(&Ws[r * LDSS + v * 4]) = wb;
        }
    };
    auto compute = [&]() {
        const int lr = lane & 15;
        const int lgg = lane >> 4;
        short8 af[4], bf[4];
        #pragma unroll
        for (int mf = 0; mf < 4; ++mf)
            af[mf] = *(const short8*)(&As[(wrr * 64 + mf * 16 + lr) * LDSS + lgg * 8]);
        #pragma unroll
        for (int nf = 0; nf < 4; ++nf)
            bf[nf] = *(const short8*)(&Ws[(wcc * 64 + nf * 16 + lr) * LDSS + lgg * 8]);
        #pragma unroll
        for (int mf = 0; mf < 4; ++mf)
            #pragma unroll
            for (int nf = 0; nf < 4; ++nf)
                acc[mf][nf] = __builtin_amdgcn_mfma_f32_16x16x32_bf16(
                    af[mf], bf[nf], acc[mf][nf], 0, 0, 0);
    };

    load_tile(0);
    for (int kb = 0; kb < K_; kb += 32) {
        __syncthreads();
        write_tile();
        __syncthreads();
        if (kb + 32 < K_) load_tile(kb + 32);
        compute();
    }
    const int lr = lane & 15;
    const int lgg = lane >> 4;
    #pragma unroll
    for (int mf = 0; mf < 4; ++mf)
        #pragma unroll
        for (int nf = 0; nf < 4; ++nf)
            #pragma unroll
            for (int j = 0; j < 4; ++j) {
                const int r = row0 + wrr * 64 + mf * 16 + lgg * 4 + j;
                const int c = col0 + wcc * 64 + nf * 16 + lr;
                C[(size_t)r * N_ + c] = acc[mf][nf][j];
            }
}

extern "C" void kernel_launch(void* const* d_in, const int* in_sizes, int n_in,
                              void* d_out, int out_size, void* d_ws, size_t ws_size,
                              hipStream_t stream) {
    const float* X  = (const float*)d_in[0];
    const int*   Q  = (const int*)d_in[1];
    const float* SZ = (const float*)d_in[2];
    float* C = (float*)d_out;

    const size_t xb_bytes = (size_t)M_ * K_ * 2;
    const size_t wb_bytes = (size_t)N_ * K_ * 2;
    if (ws_size >= xb_bytes + wb_bytes) {
        unsigned short* Xb = (unsigned short*)d_ws;
        unsigned short* Wb = (unsigned short*)((char*)d_ws + xb_bytes);
        cvt_x_kernel<<<(M_ * (K_ / 8)) / 256, 256, 0, stream>>>(X, Xb);
        deq_w_kernel<<<(N_ * (K_ / 8)) / 256, 256, 0, stream>>>(Q, SZ, Wb);
        gemm_bf16_hyb<<<dim3(2752), dim3(512), 0, stream>>>(Xb, Wb, C);
    } else {
        dim3 grid(M_ / 128, N_ / 128);
        w4_gemm_fused<<<grid, dim3(256), 0, stream>>>(X, Q, SZ, C);
    }
}

// Round 19
// 745.447 us; speedup vs baseline: 1.4722x; 1.4722x over previous
//
#include <hip/hip_runtime.h>
#include <stdint.h>

// WeightOnlyInt4Linear: y = X @ dequant(Q)^T ; M=8192, K=4096, N=11008, G=128.
// Round 19 (final): r13 restored (best measured: GEMM ~656us, MfmaUtil 52%,
// 0 bank conflicts) + prepasses merged into one launch (identical bodies,
// disjoint block ranges) to overlap their memory streams.
// r13 = r9 ring + T19 sched_group_barrier pinning of {4 MFMA, 1 ds_read}.

typedef __attribute__((ext_vector_type(8))) short short8;
typedef __attribute__((ext_vector_type(4))) float float4v;
typedef __attribute__((ext_vector_type(4))) int int4v;
typedef __attribute__((ext_vector_type(2))) float float2v;
typedef __attribute__((ext_vector_type(4))) unsigned short ushort4v;

static constexpr int M_ = 8192;
static constexpr int K_ = 4096;
static constexpr int N_ = 11008;
static constexpr int NKT = K_ / 64;  // 64 K-tiles

__device__ __forceinline__ unsigned short f2bf(float f) {
    union { float f; uint32_t u; } v;
    v.f = f;
    uint32_t u = v.u;
    u += 0x7fffu + ((u >> 16) & 1u);  // RNE
    return (unsigned short)(u >> 16);
}

__device__ __forceinline__ void gload16(const void* g, void* l) {
    __builtin_amdgcn_global_load_lds(
        (const __attribute__((address_space(1))) uint32_t*)g,
        (__attribute__((address_space(3))) uint32_t*)l, 16, 0, 0);
}

// ---------------- Merged prepass: X->bf16 and W-dequant->bf16 ----------------
// blocks [0, XB): cvt_x ; blocks [XB, XB+WB): deq_w. Bodies identical to r13.
static constexpr int XBLKS = (M_ * (K_ / 8)) / 256;   // 16384
static constexpr int WBLKS = (N_ * (K_ / 8)) / 256;   // 22016

__global__ __launch_bounds__(256) void prepass_kernel(const float* __restrict__ X,
                                                      const int* __restrict__ Q,
                                                      const float* __restrict__ SZ,
                                                      unsigned short* __restrict__ Xb,
                                                      unsigned short* __restrict__ Wb) {
    if (blockIdx.x < XBLKS) {
        const int i = blockIdx.x * 256 + threadIdx.x;
        const float4v a = ((const float4v*)X)[2 * (size_t)i];
        const float4v b = ((const float4v*)X)[2 * (size_t)i + 1];
        short8 o;
        #pragma unroll
        for (int j = 0; j < 4; ++j) o[j] = (short)f2bf(a[j]);
        #pragma unroll
        for (int j = 0; j < 4; ++j) o[4 + j] = (short)f2bf(b[j]);
        ((short8*)Xb)[(size_t)i] = o;
    } else {
        const int i = (blockIdx.x - XBLKS) * 256 + threadIdx.x;  // < N*K/8
        const int n = i >> 9;
        const int c = i & 511;
        const int k0 = c * 8;
        const int g = k0 >> 7;
        const float2v sz = *(const float2v*)(SZ + ((size_t)g * N_ + n) * 2);
        const float s = sz[0], z = sz[1];
        const int4v q0 = *(const int4v*)(Q + (size_t)n * K_ + k0);
        const int4v q1 = *(const int4v*)(Q + (size_t)n * K_ + k0 + 4);
        short8 o;
        #pragma unroll
        for (int j = 0; j < 4; ++j) o[j] = (short)f2bf((float)(q0[j] - 8) * s + z);
        #pragma unroll
        for (int j = 0; j < 4; ++j) o[4 + j] = (short)f2bf((float)(q1[j] - 8) * s + z);
        ((short8*)Wb)[(size_t)i] = o;
    }
}

// ---------------- 256x256 GEMM, SGB-pinned interleave (r13) ----------------
// LDS (bytes): A buf0 [0,32K) A buf1 [32K,64K) B buf0 [64K,96K) B buf1 [96K,128K)
// Tile: 256 rows x 64 bf16 (128 B/row); half = 128 rows = 16 KB.
// Swizzle: phys_col_byte = logical_col_byte ^ ((row&7)<<4).

#define SBAR() __builtin_amdgcn_sched_barrier(0)
#define SGB(m, n) __builtin_amdgcn_sched_group_barrier(m, n, 0)
#define VMW(n) asm volatile("s_waitcnt vmcnt(" #n ")" ::: "memory")
#define LGKM0() asm volatile("s_waitcnt lgkmcnt(0)" ::: "memory")
#define BARRIER() __builtin_amdgcn_s_barrier()
// LLVM SchedGroupMask: MFMA=0x8, DS_READ=0x100

__global__ __launch_bounds__(512, 2) void gemm_bf16_8ph(
    const unsigned short* __restrict__ Agl,  // [M][K] bf16
    const unsigned short* __restrict__ Bgl,  // [N][K] bf16
    float* __restrict__ C) {
    __shared__ alignas(16) unsigned short lds[65536];  // 128 KiB

    const int tid = threadIdx.x;
    const int lane = tid & 63;
    const int wid = tid >> 6;   // 0..7
    const int wr = wid >> 2;    // 0..1 (M sub-block within half)
    const int wc = wid & 3;     // 0..3 (N sub-block within half)

    // T1: XCD swizzle over 1376 = 8*172 blocks.
    const int bid = blockIdx.x;
    const int wg = (bid & 7) * 172 + (bid >> 3);
    const int mt = wg / 43;
    const int nt = wg % 43;
    const int row0 = mt * 256;
    const int col0 = nt * 256;

    // staging lane geometry: wave writes 8 rows x 128 B linear.
    const int r8 = lane >> 3;                // 0..7 == row&7
    const int kc = ((lane & 7) ^ r8) * 8;    // inverse-swizzled global k-elem offset

    // ds_read lane geometry: read row&7 = l15&7.
    const int l15 = lane & 15;
    const int k0o = ((lane >> 4) * 16) ^ ((l15 & 7) << 4);
    const int k1o = k0o ^ 64;
    const int aK0 = (wr * 64 + l15) * 128 + k0o;          // A ds_read bases
    const int aK1 = (wr * 64 + l15) * 128 + k1o;
    const int bK0 = 65536 + (wc * 32 + l15) * 128 + k0o;  // B bases (+64K bias)
    const int bK1 = 65536 + (wc * 32 + l15) * 128 + k1o;
    const char* ldsB = (const char*)lds;
    unsigned short* ldsU = lds;
    const char* AglB = (const char*)Agl;
    const char* BglB = (const char*)Bgl;

    // Persistent 32-bit staging byte-offsets, one per stream [h][i]; +128 B/use.
    uint32_t sA[2][2], sB[2][2];
    #pragma unroll
    for (int h = 0; h < 2; ++h)
        #pragma unroll
        for (int i = 0; i < 2; ++i) {
            sA[h][i] = (uint32_t)(row0 + h * 128 + (wid * 2 + i) * 8 + r8) * (K_ * 2)
                       + (uint32_t)kc * 2;
            sB[h][i] = (uint32_t)(col0 + h * 128 + (wid * 2 + i) * 8 + r8) * (K_ * 2)
                       + (uint32_t)kc * 2;
        }

    auto gA = [&](uint32_t& off, int b, int h, int i) {
        gload16(AglB + off, ldsU + b * 16384 + (h * 128 + (wid * 2 + i) * 8) * 64);
        off += 128;
    };
    auto gB = [&](uint32_t& off, int b, int h, int i) {
        gload16(BglB + off, ldsU + 32768 + b * 16384 + (h * 128 + (wid * 2 + i) * 8) * 64);
        off += 128;
    };

    float4v acc[8][4] = {};
    short8 a0[4][2], a1[4][2];  // A h0/h1 fragments (persist across tiles)
    short8 b0[2][2], b1[2][2];  // B h0/h1 fragments

#define MMA2(MH, NH, I, J, A, B)                                              \
    acc[(MH)*4+(I)][(NH)*2+(J)] = __builtin_amdgcn_mfma_f32_16x16x32_bf16(    \
        A[I][0], B[J][0], acc[(MH)*4+(I)][(NH)*2+(J)], 0, 0, 0);              \
    acc[(MH)*4+(I)][(NH)*2+(J)] = __builtin_amdgcn_mfma_f32_16x16x32_bf16(    \
        A[I][1], B[J][1], acc[(MH)*4+(I)][(NH)*2+(J)], 0, 0, 0);
#define RDA(DST, BASE, I)                                                     \
    DST[I][0] = *(const short8*)(ldsB + (BASE) + (I)*2048 + aK0);             \
    DST[I][1] = *(const short8*)(ldsB + (BASE) + (I)*2048 + aK1);
#define RDB(DST, BASE, J)                                                     \
    DST[J][0] = *(const short8*)(ldsB + (BASE) + (J)*2048 + bK0);             \
    DST[J][1] = *(const short8*)(ldsB + (BASE) + (J)*2048 + bK1);
// SGB pin patterns (counts must match region contents exactly)
#define PIN_32M_8R()                                                          \
    SGB(0x8, 4); SGB(0x100, 1); SGB(0x8, 4); SGB(0x100, 1);                   \
    SGB(0x8, 4); SGB(0x100, 1); SGB(0x8, 4); SGB(0x100, 1);                   \
    SGB(0x8, 4); SGB(0x100, 1); SGB(0x8, 4); SGB(0x100, 1);                   \
    SGB(0x8, 4); SGB(0x100, 1); SGB(0x8, 4); SGB(0x100, 1);
#define PIN_32M_4R()                                                          \
    SGB(0x8, 4); SGB(0x100, 1); SGB(0x8, 4); SGB(0x100, 1);                   \
    SGB(0x8, 4); SGB(0x100, 1); SGB(0x8, 4); SGB(0x100, 1);                   \
    SGB(0x8, 16);
#define PIN_32M()  SGB(0x8, 32);

    // Prologue: tile 0 -> buf0 (A0,A1,B0,B1) + A0(1) -> buf1; VMW(2) leaves
    // the A0(1) pair in flight; read a0,b0 of tile 0.
    gA(sA[0][0], 0, 0, 0); gA(sA[0][1], 0, 0, 1);
    gA(sA[1][0], 0, 1, 0); gA(sA[1][1], 0, 1, 1);
    gB(sB[0][0], 0, 0, 0); gB(sB[0][1], 0, 0, 1);
    gB(sB[1][0], 0, 1, 0); gB(sB[1][1], 0, 1, 1);
    gA(sA[0][0], 1, 0, 0); gA(sA[0][1], 1, 0, 1);  // A0(1) -> buf1, stays in flight
    VMW(2);
    BARRIER(); SBAR();
    RDA(a0, 0, 0) RDA(a0, 0, 1) RDA(a0, 0, 2) RDA(a0, 0, 3)
    RDB(b0, 0, 0) RDB(b0, 0, 1)
    LGKM0(); SBAR();

    // Per tile t (BUF=t&1):
    // P1: stage S1->BUF^1 ; mma<0,0>(a0,b0) ∥ read a1<-BUF      [32M+8R pinned]
    // P2: stage S2->BUF^1 ; mma<1,0>(a1,b0) ∥ read b1<-BUF      [32M+4R]
    // MID: stage S3->BUF ; VMW(MIDW) ; BAR
    // P3: mma<0,1>(a0,b1) ∥ read b0'<-BUF^1 (WAR safe)          [32M+4R]
    // P4: mma<1,1>(a1,b1) ∥ read a0'<-BUF^1                     [32M+8R]
    // END: VMW(ENDW) ; BAR ; lgkmcnt(0)
#define KTILE(BUF, DN, DN2, MIDW, ENDW, DOEND)                                \
    {                                                                         \
        constexpr int CB = (BUF) * 32768;                                     \
        constexpr int NB = ((BUF) ^ 1) * 32768;                               \
        /* ---- P1 ---- */                                                    \
        if (DN) {                                                             \
            gA(sA[1][0], (BUF) ^ 1, 1, 0); gA(sA[1][1], (BUF) ^ 1, 1, 1);     \
            gB(sB[0][0], (BUF) ^ 1, 0, 0); gB(sB[0][1], (BUF) ^ 1, 0, 1);     \
        }                                                                     \
        __builtin_amdgcn_s_setprio(1);                                        \
        MMA2(0, 0, 0, 0, a0, b0) RDA(a1, CB + 16384, 0)                       \
        MMA2(0, 0, 0, 1, a0, b0) RDA(a1, CB + 16384, 1)                       \
        MMA2(0, 0, 1, 0, a0, b0) RDA(a1, CB + 16384, 2)                       \
        MMA2(0, 0, 1, 1, a0, b0) RDA(a1, CB + 16384, 3)                       \
        MMA2(0, 0, 2, 0, a0, b0) MMA2(0, 0, 2, 1, a0, b0)                     \
        MMA2(0, 0, 3, 0, a0, b0) MMA2(0, 0, 3, 1, a0, b0)                     \
        if (DN) { PIN_32M_8R() } else { PIN_32M() }                           \
        __builtin_amdgcn_s_setprio(0);                                        \
        LGKM0(); SBAR();                                                      \
        /* ---- P2 ---- */                                                    \
        if (DN) { gB(sB[1][0], (BUF) ^ 1, 1, 0); gB(sB[1][1], (BUF) ^ 1, 1, 1); } \
        __builtin_amdgcn_s_setprio(1);                                        \
        MMA2(1, 0, 0, 0, a1, b0) RDB(b1, CB + 16384, 0)                       \
        MMA2(1, 0, 0, 1, a1, b0) RDB(b1, CB + 16384, 1)                       \
        MMA2(1, 0, 1, 0, a1, b0) MMA2(1, 0, 1, 1, a1, b0)                     \
        MMA2(1, 0, 2, 0, a1, b0) MMA2(1, 0, 2, 1, a1, b0)                     \
        MMA2(1, 0, 3, 0, a1, b0) MMA2(1, 0, 3, 1, a1, b0)                     \
        PIN_32M_4R()                                                          \
        __builtin_amdgcn_s_setprio(0);                                        \
        LGKM0(); SBAR();                                                      \
        /* ---- MID sync ---- */                                              \
        if (DN2) { gA(sA[0][0], BUF, 0, 0); gA(sA[0][1], BUF, 0, 1); }        \
        VMW(MIDW);                                                            \
        BARRIER(); SBAR();                                                    \
        /* ---- P3 ---- */                                                    \
        __builtin_amdgcn_s_setprio(1);                                        \
        MMA2(0, 1, 0, 0, a0, b1)                                              \
        if (DN) { RDB(b0, NB, 0) }                                            \
        MMA2(0, 1, 0, 1, a0, b1)                                              \
        if (DN) { RDB(b0, NB, 1) }                                            \
        MMA2(0, 1, 1, 0, a0, b1) MMA2(0, 1, 1, 1, a0, b1)                     \
        MMA2(0, 1, 2, 0, a0, b1) MMA2(0, 1, 2, 1, a0, b1)                     \
        MMA2(0, 1, 3, 0, a0, b1) MMA2(0, 1, 3, 1, a0, b1)                     \
        if (DN) { PIN_32M_4R() } else { PIN_32M() }                           \
        __builtin_amdgcn_s_setprio(0);                                        \
        SBAR();                                                               \
        /* ---- P4 ---- */                                                    \
        __builtin_amdgcn_s_setprio(1);                                        \
        MMA2(1, 1, 0, 0, a1, b1)                                              \
        if (DN) { RDA(a0, NB, 0) }                                            \
        MMA2(1, 1, 0, 1, a1, b1)                                              \
        if (DN) { RDA(a0, NB, 1) }                                            \
        MMA2(1, 1, 1, 0, a1, b1)                                              \
        if (DN) { RDA(a0, NB, 2) }                                            \
        MMA2(1, 1, 1, 1, a1, b1)                                              \
        if (DN) { RDA(a0, NB, 3) }                                            \
        MMA2(1, 1, 2, 0, a1, b1) MMA2(1, 1, 2, 1, a1, b1)                     \
        MMA2(1, 1, 3, 0, a1, b1) MMA2(1, 1, 3, 1, a1, b1)                     \
        if (DN) { PIN_32M_8R() } else { PIN_32M() }                           \
        __builtin_amdgcn_s_setprio(0);                                        \
        if (DOEND) {                                                          \
            VMW(ENDW);                                                        \
            BARRIER(); SBAR();                                                \
            LGKM0(); SBAR();                                                  \
        }                                                                     \
    }

    for (int t2 = 0; t2 < NKT - 2; t2 += 2) {
        KTILE(0, 1, 1, 4, 2, 1);
        KTILE(1, 1, 1, 4, 2, 1);
    }
    KTILE(0, 1, 0, 2, 0, 1);  // t=62: no S3; MID drains S3(61)+S1(62); END drains S2(62)
    KTILE(1, 0, 0, 0, 0, 0);  // t=63: pure compute
#undef KTILE
#undef MMA2
#undef RDA
#undef RDB

    // Epilogue: D map col=lane&15, row=(lane>>4)*4+j (m89-verified).
    const int lrow = (lane >> 4) * 4;
    #pragma unroll
    for (int mf = 0; mf < 8; ++mf)
        #pragma unroll
        for (int nf = 0; nf < 4; ++nf)
            #pragma unroll
            for (int j = 0; j < 4; ++j) {
                const int r = row0 + (mf >> 2) * 128 + wr * 64 + (mf & 3) * 16 + lrow + j;
                const int c = col0 + (nf >> 1) * 128 + wc * 32 + (nf & 1) * 16 + l15;
                C[(size_t)r * N_ + c] = acc[mf][nf][j];
            }
}

// ---------------- Fallback: round-1 fused kernel ----------------
static constexpr int LDSS = 40;

__global__ __launch_bounds__(256, 2) void w4_gemm_fused(
    const float* __restrict__ X, const int* __restrict__ Q,
    const float* __restrict__ SZ, float* __restrict__ C) {
    __shared__ alignas(16) unsigned short As[128 * LDSS];
    __shared__ alignas(16) unsigned short Ws[128 * LDSS];
    const int tid = threadIdx.x;
    const int lane = tid & 63;
    const int wid = tid >> 6;
    const int wrr = wid >> 1;
    const int wcc = wid & 1;
    const int row0 = blockIdx.x * 128;
    const int col0 = blockIdx.y * 128;
    float4v acc[4][4] = {};
    float4v a_reg[4];
    int4v q_reg[4];
    float2v sz_reg[4];

    auto load_tile = [&](int kb) {
        const int g = kb >> 7;
        #pragma unroll
        for (int i = 0; i < 4; ++i) {
            const int idx = tid + 256 * i;
            const int r = idx >> 3;
            const int v = idx & 7;
            a_reg[i] = *(const float4v*)(X + (size_t)(row0 + r) * K_ + kb + v * 4);
            q_reg[i] = *(const int4v*)(Q + (size_t)(col0 + r) * K_ + kb + v * 4);
            sz_reg[i] = *(const float2v*)(SZ + ((size_t)g * N_ + (col0 + r)) * 2);
        }
    };
    auto write_tile = [&]() {
        #pragma unroll
        for (int i = 0; i < 4; ++i) {
            const int idx = tid + 256 * i;
            const int r = idx >> 3;
            const int v = idx & 7;
            ushort4v ab, wb;
            #pragma unroll
            for (int j = 0; j < 4; ++j) ab[j] = f2bf(a_reg[i][j]);
            const float s = sz_reg[i][0];
            const float z = sz_reg[i][1];
            #pragma unroll
            for (int j = 0; j < 4; ++j) wb[j] = f2bf((float)(q_reg[i][j] - 8) * s + z);
            *(ushort4v*)(&As[r * LDSS + v * 4]) = ab;
            *(ushort4v*)(&Ws[r * LDSS + v * 4]) = wb;
        }
    };
    auto compute = [&]() {
        const int lr = lane & 15;
        const int lgg = lane >> 4;
        short8 af[4], bf[4];
        #pragma unroll
        for (int mf = 0; mf < 4; ++mf)
            af[mf] = *(const short8*)(&As[(wrr * 64 + mf * 16 + lr) * LDSS + lgg * 8]);
        #pragma unroll
        for (int nf = 0; nf < 4; ++nf)
            bf[nf] = *(const short8*)(&Ws[(wcc * 64 + nf * 16 + lr) * LDSS + lgg * 8]);
        #pragma unroll
        for (int mf = 0; mf < 4; ++mf)
            #pragma unroll
            for (int nf = 0; nf < 4; ++nf)
                acc[mf][nf] = __builtin_amdgcn_mfma_f32_16x16x32_bf16(
                    af[mf], bf[nf], acc[mf][nf], 0, 0, 0);
    };

    load_tile(0);
    for (int kb = 0; kb < K_; kb += 32) {
        __syncthreads();
        write_tile();
        __syncthreads();
        if (kb + 32 < K_) load_tile(kb + 32);
        compute();
    }
    const int lr = lane & 15;
    const int lgg = lane >> 4;
    #pragma unroll
    for (int mf = 0; mf < 4; ++mf)
        #pragma unroll
        for (int nf = 0; nf < 4; ++nf)
            #pragma unroll
            for (int j = 0; j < 4; ++j) {
                const int r = row0 + wrr * 64 + mf * 16 + lgg * 4 + j;
                const int c = col0 + wcc * 64 + nf * 16 + lr;
                C[(size_t)r * N_ + c] = acc[mf][nf][j];
            }
}

extern "C" void kernel_launch(void* const* d_in, const int* in_sizes, int n_in,
                              void* d_out, int out_size, void* d_ws, size_t ws_size,
                              hipStream_t stream) {
    const float* X  = (const float*)d_in[0];
    const int*   Q  = (const int*)d_in[1];
    const float* SZ = (const float*)d_in[2];
    float* C = (float*)d_out;

    const size_t xb_bytes = (size_t)M_ * K_ * 2;
    const size_t wb_bytes = (size_t)N_ * K_ * 2;
    if (ws_size >= xb_bytes + wb_bytes) {
        unsigned short* Xb = (unsigned short*)d_ws;
        unsigned short* Wb = (unsigned short*)((char*)d_ws + xb_bytes);
        prepass_kernel<<<XBLKS + WBLKS, 256, 0, stream>>>(X, Q, SZ, Xb, Wb);
        gemm_bf16_8ph<<<dim3(1376), dim3(512), 0, stream>>>(Xb, Wb, C);
    } else {
        dim3 grid(M_ / 128, N_ / 128);
        w4_gemm_fused<<<grid, dim3(256), 0, stream>>>(X, Q, SZ, C);
    }
}

// Round 20
// 743.447 us; speedup vs baseline: 1.4761x; 1.0027x over previous
//
#include <hip/hip_runtime.h>
#include <stdint.h>

// WeightOnlyInt4Linear: y = X @ dequant(Q)^T ; M=8192, K=4096, N=11008, G=128.
// FINAL (r13 verbatim, best measured: total 740us, GEMM ~656us, MfmaUtil 52%,
// 0 bank conflicts): prepass dequant to bf16 in d_ws + 256x256 GEMM with the
// r9 staging ring and T19 sched_group_barrier pinning of {4 MFMA, 1 ds_read}.
// Ring: S1={A1',B0'}@P1, S2={B1'}@P2, S3={A0''->BUF}@mid; MID=VMW(4)+BAR,
// END=VMW(2)+BAR; tail 2/0. Swizzle: byte ^= (row&7)<<4 (both-sides).

typedef __attribute__((ext_vector_type(8))) short short8;
typedef __attribute__((ext_vector_type(4))) float float4v;
typedef __attribute__((ext_vector_type(4))) int int4v;
typedef __attribute__((ext_vector_type(2))) float float2v;
typedef __attribute__((ext_vector_type(4))) unsigned short ushort4v;

static constexpr int M_ = 8192;
static constexpr int K_ = 4096;
static constexpr int N_ = 11008;
static constexpr int NKT = K_ / 64;  // 64 K-tiles

__device__ __forceinline__ unsigned short f2bf(float f) {
    union { float f; uint32_t u; } v;
    v.f = f;
    uint32_t u = v.u;
    u += 0x7fffu + ((u >> 16) & 1u);  // RNE
    return (unsigned short)(u >> 16);
}

__device__ __forceinline__ void gload16(const void* g, void* l) {
    __builtin_amdgcn_global_load_lds(
        (const __attribute__((address_space(1))) uint32_t*)g,
        (__attribute__((address_space(3))) uint32_t*)l, 16, 0, 0);
}

// ---------------- Prepass 1: X fp32 -> bf16 ----------------
__global__ __launch_bounds__(256) void cvt_x_kernel(const float* __restrict__ X,
                                                    unsigned short* __restrict__ Xb) {
    const int i = blockIdx.x * 256 + threadIdx.x;
    const float4v a = ((const float4v*)X)[2 * (size_t)i];
    const float4v b = ((const float4v*)X)[2 * (size_t)i + 1];
    short8 o;
    #pragma unroll
    for (int j = 0; j < 4; ++j) o[j] = (short)f2bf(a[j]);
    #pragma unroll
    for (int j = 0; j < 4; ++j) o[4 + j] = (short)f2bf(b[j]);
    ((short8*)Xb)[(size_t)i] = o;
}

// ---------------- Prepass 2: W int4 codes -> bf16 ----------------
__global__ __launch_bounds__(256) void deq_w_kernel(const int* __restrict__ Q,
                                                    const float* __restrict__ SZ,
                                                    unsigned short* __restrict__ Wb) {
    const int i = blockIdx.x * 256 + threadIdx.x;  // < N*K/8
    const int n = i >> 9;
    const int c = i & 511;
    const int k0 = c * 8;
    const int g = k0 >> 7;
    const float2v sz = *(const float2v*)(SZ + ((size_t)g * N_ + n) * 2);
    const float s = sz[0], z = sz[1];
    const int4v q0 = *(const int4v*)(Q + (size_t)n * K_ + k0);
    const int4v q1 = *(const int4v*)(Q + (size_t)n * K_ + k0 + 4);
    short8 o;
    #pragma unroll
    for (int j = 0; j < 4; ++j) o[j] = (short)f2bf((float)(q0[j] - 8) * s + z);
    #pragma unroll
    for (int j = 0; j < 4; ++j) o[4 + j] = (short)f2bf((float)(q1[j] - 8) * s + z);
    ((short8*)Wb)[(size_t)i] = o;
}

// ---------------- 256x256 GEMM, SGB-pinned interleave ----------------
// LDS (bytes): A buf0 [0,32K) A buf1 [32K,64K) B buf0 [64K,96K) B buf1 [96K,128K)
// Tile: 256 rows x 64 bf16 (128 B/row); half = 128 rows = 16 KB.

#define SBAR() __builtin_amdgcn_sched_barrier(0)
#define SGB(m, n) __builtin_amdgcn_sched_group_barrier(m, n, 0)
#define VMW(n) asm volatile("s_waitcnt vmcnt(" #n ")" ::: "memory")
#define LGKM0() asm volatile("s_waitcnt lgkmcnt(0)" ::: "memory")
#define BARRIER() __builtin_amdgcn_s_barrier()
// LLVM SchedGroupMask: MFMA=0x8, DS_READ=0x100

__global__ __launch_bounds__(512, 2) void gemm_bf16_8ph(
    const unsigned short* __restrict__ Agl,  // [M][K] bf16
    const unsigned short* __restrict__ Bgl,  // [N][K] bf16
    float* __restrict__ C) {
    __shared__ alignas(16) unsigned short lds[65536];  // 128 KiB

    const int tid = threadIdx.x;
    const int lane = tid & 63;
    const int wid = tid >> 6;   // 0..7
    const int wr = wid >> 2;    // 0..1 (M sub-block within half)
    const int wc = wid & 3;     // 0..3 (N sub-block within half)

    // T1: XCD swizzle over 1376 = 8*172 blocks.
    const int bid = blockIdx.x;
    const int wg = (bid & 7) * 172 + (bid >> 3);
    const int mt = wg / 43;
    const int nt = wg % 43;
    const int row0 = mt * 256;
    const int col0 = nt * 256;

    // staging lane geometry: wave writes 8 rows x 128 B linear.
    const int r8 = lane >> 3;                // 0..7 == row&7
    const int kc = ((lane & 7) ^ r8) * 8;    // inverse-swizzled global k-elem offset

    // ds_read lane geometry: read row&7 = l15&7.
    const int l15 = lane & 15;
    const int k0o = ((lane >> 4) * 16) ^ ((l15 & 7) << 4);
    const int k1o = k0o ^ 64;
    const int aK0 = (wr * 64 + l15) * 128 + k0o;          // A ds_read bases
    const int aK1 = (wr * 64 + l15) * 128 + k1o;
    const int bK0 = 65536 + (wc * 32 + l15) * 128 + k0o;  // B bases (+64K bias)
    const int bK1 = 65536 + (wc * 32 + l15) * 128 + k1o;
    const char* ldsB = (const char*)lds;
    unsigned short* ldsU = lds;
    const char* AglB = (const char*)Agl;
    const char* BglB = (const char*)Bgl;

    // Persistent 32-bit staging byte-offsets, one per stream [h][i]; +128 B/use.
    uint32_t sA[2][2], sB[2][2];
    #pragma unroll
    for (int h = 0; h < 2; ++h)
        #pragma unroll
        for (int i = 0; i < 2; ++i) {
            sA[h][i] = (uint32_t)(row0 + h * 128 + (wid * 2 + i) * 8 + r8) * (K_ * 2)
                       + (uint32_t)kc * 2;
            sB[h][i] = (uint32_t)(col0 + h * 128 + (wid * 2 + i) * 8 + r8) * (K_ * 2)
                       + (uint32_t)kc * 2;
        }

    auto gA = [&](uint32_t& off, int b, int h, int i) {
        gload16(AglB + off, ldsU + b * 16384 + (h * 128 + (wid * 2 + i) * 8) * 64);
        off += 128;
    };
    auto gB = [&](uint32_t& off, int b, int h, int i) {
        gload16(BglB + off, ldsU + 32768 + b * 16384 + (h * 128 + (wid * 2 + i) * 8) * 64);
        off += 128;
    };

    float4v acc[8][4] = {};
    short8 a0[4][2], a1[4][2];  // A h0/h1 fragments (persist across tiles)
    short8 b0[2][2], b1[2][2];  // B h0/h1 fragments

#define MMA2(MH, NH, I, J, A, B)                                              \
    acc[(MH)*4+(I)][(NH)*2+(J)] = __builtin_amdgcn_mfma_f32_16x16x32_bf16(    \
        A[I][0], B[J][0], acc[(MH)*4+(I)][(NH)*2+(J)], 0, 0, 0);              \
    acc[(MH)*4+(I)][(NH)*2+(J)] = __builtin_amdgcn_mfma_f32_16x16x32_bf16(    \
        A[I][1], B[J][1], acc[(MH)*4+(I)][(NH)*2+(J)], 0, 0, 0);
#define RDA(DST, BASE, I)                                                     \
    DST[I][0] = *(const short8*)(ldsB + (BASE) + (I)*2048 + aK0);             \
    DST[I][1] = *(const short8*)(ldsB + (BASE) + (I)*2048 + aK1);
#define RDB(DST, BASE, J)                                                     \
    DST[J][0] = *(const short8*)(ldsB + (BASE) + (J)*2048 + bK0);             \
    DST[J][1] = *(const short8*)(ldsB + (BASE) + (J)*2048 + bK1);
// SGB pin patterns (counts must match region contents exactly)
#define PIN_32M_8R()                                                          \
    SGB(0x8, 4); SGB(0x100, 1); SGB(0x8, 4); SGB(0x100, 1);                   \
    SGB(0x8, 4); SGB(0x100, 1); SGB(0x8, 4); SGB(0x100, 1);                   \
    SGB(0x8, 4); SGB(0x100, 1); SGB(0x8, 4); SGB(0x100, 1);                   \
    SGB(0x8, 4); SGB(0x100, 1); SGB(0x8, 4); SGB(0x100, 1);
#define PIN_32M_4R()                                                          \
    SGB(0x8, 4); SGB(0x100, 1); SGB(0x8, 4); SGB(0x100, 1);                   \
    SGB(0x8, 4); SGB(0x100, 1); SGB(0x8, 4); SGB(0x100, 1);                   \
    SGB(0x8, 16);
#define PIN_32M()  SGB(0x8, 32);

    // Prologue: tile 0 -> buf0 (A0,A1,B0,B1) + A0(1) -> buf1; VMW(2) leaves
    // the A0(1) pair in flight; read a0,b0 of tile 0.
    gA(sA[0][0], 0, 0, 0); gA(sA[0][1], 0, 0, 1);
    gA(sA[1][0], 0, 1, 0); gA(sA[1][1], 0, 1, 1);
    gB(sB[0][0], 0, 0, 0); gB(sB[0][1], 0, 0, 1);
    gB(sB[1][0], 0, 1, 0); gB(sB[1][1], 0, 1, 1);
    gA(sA[0][0], 1, 0, 0); gA(sA[0][1], 1, 0, 1);  // A0(1) -> buf1, stays in flight
    VMW(2);
    BARRIER(); SBAR();
    RDA(a0, 0, 0) RDA(a0, 0, 1) RDA(a0, 0, 2) RDA(a0, 0, 3)
    RDB(b0, 0, 0) RDB(b0, 0, 1)
    LGKM0(); SBAR();

    // Per tile t (BUF=t&1):
    // P1: stage S1->BUF^1 ; mma<0,0>(a0,b0) ∥ read a1<-BUF      [32M+8R pinned]
    // P2: stage S2->BUF^1 ; mma<1,0>(a1,b0) ∥ read b1<-BUF      [32M+4R]
    // MID: stage S3->BUF ; VMW(MIDW) ; BAR
    // P3: mma<0,1>(a0,b1) ∥ read b0'<-BUF^1 (WAR safe)          [32M+4R]
    // P4: mma<1,1>(a1,b1) ∥ read a0'<-BUF^1                     [32M+8R]
    // END: VMW(ENDW) ; BAR ; lgkmcnt(0)
#define KTILE(BUF, DN, DN2, MIDW, ENDW, DOEND)                                \
    {                                                                         \
        constexpr int CB = (BUF) * 32768;                                     \
        constexpr int NB = ((BUF) ^ 1) * 32768;                               \
        /* ---- P1 ---- */                                                    \
        if (DN) {                                                             \
            gA(sA[1][0], (BUF) ^ 1, 1, 0); gA(sA[1][1], (BUF) ^ 1, 1, 1);     \
            gB(sB[0][0], (BUF) ^ 1, 0, 0); gB(sB[0][1], (BUF) ^ 1, 0, 1);     \
        }                                                                     \
        __builtin_amdgcn_s_setprio(1);                                        \
        MMA2(0, 0, 0, 0, a0, b0) RDA(a1, CB + 16384, 0)                       \
        MMA2(0, 0, 0, 1, a0, b0) RDA(a1, CB + 16384, 1)                       \
        MMA2(0, 0, 1, 0, a0, b0) RDA(a1, CB + 16384, 2)                       \
        MMA2(0, 0, 1, 1, a0, b0) RDA(a1, CB + 16384, 3)                       \
        MMA2(0, 0, 2, 0, a0, b0) MMA2(0, 0, 2, 1, a0, b0)                     \
        MMA2(0, 0, 3, 0, a0, b0) MMA2(0, 0, 3, 1, a0, b0)                     \
        if (DN) { PIN_32M_8R() } else { PIN_32M() }                           \
        __builtin_amdgcn_s_setprio(0);                                        \
        LGKM0(); SBAR();                                                      \
        /* ---- P2 ---- */                                                    \
        if (DN) { gB(sB[1][0], (BUF) ^ 1, 1, 0); gB(sB[1][1], (BUF) ^ 1, 1, 1); } \
        __builtin_amdgcn_s_setprio(1);                                        \
        MMA2(1, 0, 0, 0, a1, b0) RDB(b1, CB + 16384, 0)                       \
        MMA2(1, 0, 0, 1, a1, b0) RDB(b1, CB + 16384, 1)                       \
        MMA2(1, 0, 1, 0, a1, b0) MMA2(1, 0, 1, 1, a1, b0)                     \
        MMA2(1, 0, 2, 0, a1, b0) MMA2(1, 0, 2, 1, a1, b0)                     \
        MMA2(1, 0, 3, 0, a1, b0) MMA2(1, 0, 3, 1, a1, b0)                     \
        PIN_32M_4R()                                                          \
        __builtin_amdgcn_s_setprio(0);                                        \
        LGKM0(); SBAR();                                                      \
        /* ---- MID sync ---- */                                              \
        if (DN2) { gA(sA[0][0], BUF, 0, 0); gA(sA[0][1], BUF, 0, 1); }        \
        VMW(MIDW);                                                            \
        BARRIER(); SBAR();                                                    \
        /* ---- P3 ---- */                                                    \
        __builtin_amdgcn_s_setprio(1);                                        \
        MMA2(0, 1, 0, 0, a0, b1)                                              \
        if (DN) { RDB(b0, NB, 0) }                                            \
        MMA2(0, 1, 0, 1, a0, b1)                                              \
        if (DN) { RDB(b0, NB, 1) }                                            \
        MMA2(0, 1, 1, 0, a0, b1) MMA2(0, 1, 1, 1, a0, b1)                     \
        MMA2(0, 1, 2, 0, a0, b1) MMA2(0, 1, 2, 1, a0, b1)                     \
        MMA2(0, 1, 3, 0, a0, b1) MMA2(0, 1, 3, 1, a0, b1)                     \
        if (DN) { PIN_32M_4R() } else { PIN_32M() }                           \
        __builtin_amdgcn_s_setprio(0);                                        \
        SBAR();                                                               \
        /* ---- P4 ---- */                                                    \
        __builtin_amdgcn_s_setprio(1);                                        \
        MMA2(1, 1, 0, 0, a1, b1)                                              \
        if (DN) { RDA(a0, NB, 0) }                                            \
        MMA2(1, 1, 0, 1, a1, b1)                                              \
        if (DN) { RDA(a0, NB, 1) }                                            \
        MMA2(1, 1, 1, 0, a1, b1)                                              \
        if (DN) { RDA(a0, NB, 2) }                                            \
        MMA2(1, 1, 1, 1, a1, b1)                                              \
        if (DN) { RDA(a0, NB, 3) }                                            \
        MMA2(1, 1, 2, 0, a1, b1) MMA2(1, 1, 2, 1, a1, b1)                     \
        MMA2(1, 1, 3, 0, a1, b1) MMA2(1, 1, 3, 1, a1, b1)                     \
        if (DN) { PIN_32M_8R() } else { PIN_32M() }                           \
        __builtin_amdgcn_s_setprio(0);                                        \
        if (DOEND) {                                                          \
            VMW(ENDW);                                                        \
            BARRIER(); SBAR();                                                \
            LGKM0(); SBAR();                                                  \
        }                                                                     \
    }

    for (int t2 = 0; t2 < NKT - 2; t2 += 2) {
        KTILE(0, 1, 1, 4, 2, 1);
        KTILE(1, 1, 1, 4, 2, 1);
    }
    KTILE(0, 1, 0, 2, 0, 1);  // t=62: no S3; MID drains S3(61)+S1(62); END drains S2(62)
    KTILE(1, 0, 0, 0, 0, 0);  // t=63: pure compute
#undef KTILE
#undef MMA2
#undef RDA
#undef RDB

    // Epilogue: D map col=lane&15, row=(lane>>4)*4+j (m89-verified).
    const int lrow = (lane >> 4) * 4;
    #pragma unroll
    for (int mf = 0; mf < 8; ++mf)
        #pragma unroll
        for (int nf = 0; nf < 4; ++nf)
            #pragma unroll
            for (int j = 0; j < 4; ++j) {
                const int r = row0 + (mf >> 2) * 128 + wr * 64 + (mf & 3) * 16 + lrow + j;
                const int c = col0 + (nf >> 1) * 128 + wc * 32 + (nf & 1) * 16 + l15;
                C[(size_t)r * N_ + c] = acc[mf][nf][j];
            }
}

// ---------------- Fallback: round-1 fused kernel ----------------
static constexpr int LDSS = 40;

__global__ __launch_bounds__(256, 2) void w4_gemm_fused(
    const float* __restrict__ X, const int* __restrict__ Q,
    const float* __restrict__ SZ, float* __restrict__ C) {
    __shared__ alignas(16) unsigned short As[128 * LDSS];
    __shared__ alignas(16) unsigned short Ws[128 * LDSS];
    const int tid = threadIdx.x;
    const int lane = tid & 63;
    const int wid = tid >> 6;
    const int wrr = wid >> 1;
    const int wcc = wid & 1;
    const int row0 = blockIdx.x * 128;
    const int col0 = blockIdx.y * 128;
    float4v acc[4][4] = {};
    float4v a_reg[4];
    int4v q_reg[4];
    float2v sz_reg[4];

    auto load_tile = [&](int kb) {
        const int g = kb >> 7;
        #pragma unroll
        for (int i = 0; i < 4; ++i) {
            const int idx = tid + 256 * i;
            const int r = idx >> 3;
            const int v = idx & 7;
            a_reg[i] = *(const float4v*)(X + (size_t)(row0 + r) * K_ + kb + v * 4);
            q_reg[i] = *(const int4v*)(Q + (size_t)(col0 + r) * K_ + kb + v * 4);
            sz_reg[i] = *(const float2v*)(SZ + ((size_t)g * N_ + (col0 + r)) * 2);
        }
    };
    auto write_tile = [&]() {
        #pragma unroll
        for (int i = 0; i < 4; ++i) {
            const int idx = tid + 256 * i;
            const int r = idx >> 3;
            const int v = idx & 7;
            ushort4v ab, wb;
            #pragma unroll
            for (int j = 0; j < 4; ++j) ab[j] = f2bf(a_reg[i][j]);
            const float s = sz_reg[i][0];
            const float z = sz_reg[i][1];
            #pragma unroll
            for (int j = 0; j < 4; ++j) wb[j] = f2bf((float)(q_reg[i][j] - 8) * s + z);
            *(ushort4v*)(&As[r * LDSS + v * 4]) = ab;
            *(ushort4v*)(&Ws[r * LDSS + v * 4]) = wb;
        }
    };
    auto compute = [&]() {
        const int lr = lane & 15;
        const int lgg = lane >> 4;
        short8 af[4], bf[4];
        #pragma unroll
        for (int mf = 0; mf < 4; ++mf)
            af[mf] = *(const short8*)(&As[(wrr * 64 + mf * 16 + lr) * LDSS + lgg * 8]);
        #pragma unroll
        for (int nf = 0; nf < 4; ++nf)
            bf[nf] = *(const short8*)(&Ws[(wcc * 64 + nf * 16 + lr) * LDSS + lgg * 8]);
        #pragma unroll
        for (int mf = 0; mf < 4; ++mf)
            #pragma unroll
            for (int nf = 0; nf < 4; ++nf)
                acc[mf][nf] = __builtin_amdgcn_mfma_f32_16x16x32_bf16(
                    af[mf], bf[nf], acc[mf][nf], 0, 0, 0);
    };

    load_tile(0);
    for (int kb = 0; kb < K_; kb += 32) {
        __syncthreads();
        write_tile();
        __syncthreads();
        if (kb + 32 < K_) load_tile(kb + 32);
        compute();
    }
    const int lr = lane & 15;
    const int lgg = lane >> 4;
    #pragma unroll
    for (int mf = 0; mf < 4; ++mf)
        #pragma unroll
        for (int nf = 0; nf < 4; ++nf)
            #pragma unroll
            for (int j = 0; j < 4; ++j) {
                const int r = row0 + wrr * 64 + mf * 16 + lgg * 4 + j;
                const int c = col0 + wcc * 64 + nf * 16 + lr;
                C[(size_t)r * N_ + c] = acc[mf][nf][j];
            }
}

extern "C" void kernel_launch(void* const* d_in, const int* in_sizes, int n_in,
                              void* d_out, int out_size, void* d_ws, size_t ws_size,
                              hipStream_t stream) {
    const float* X  = (const float*)d_in[0];
    const int*   Q  = (const int*)d_in[1];
    const float* SZ = (const float*)d_in[2];
    float* C = (float*)d_out;

    const size_t xb_bytes = (size_t)M_ * K_ * 2;
    const size_t wb_bytes = (size_t)N_ * K_ * 2;
    if (ws_size >= xb_bytes + wb_bytes) {
        unsigned short* Xb = (unsigned short*)d_ws;
        unsigned short* Wb = (unsigned short*)((char*)d_ws + xb_bytes);
        cvt_x_kernel<<<(M_ * (K_ / 8)) / 256, 256, 0, stream>>>(X, Xb);
        deq_w_kernel<<<(N_ * (K_ / 8)) / 256, 256, 0, stream>>>(Q, SZ, Wb);
        gemm_bf16_8ph<<<dim3(1376), dim3(512), 0, stream>>>(Xb, Wb, C);
    } else {
        dim3 grid(M_ / 128, N_ / 128);
        w4_gemm_fused<<<grid, dim3(256), 0, stream>>>(X, Q, SZ, C);
    }
}